// Round 7
// baseline (170.368 us; speedup 1.0000x reference)
//
#include <hip/hip_runtime.h>
#include <math.h>

static constexpr int TB = 64;   // batch
static constexpr int LL = 32;   // labels
static constexpr int SS = 256;  // max target length
static constexpr int STRIDE_T = TB * LL;  // floats per time step (2048)

// FCC chunking: NCH chunks -> chunk0 (fwd, init), NI interior (fwd+bwd), last (bwd)
static constexpr int NCH = 16;
static constexpr int NI  = NCH - 2;             // 14 interior
static constexpr int NSCAN = 2 + 2 * NI;        // 30 scans per batch

// ---- workspace layout (floats per batch) --------------------------------
// FCC slots (33 floats): 0=a, 1=c, 2j=p_j, 2j+1=q_j (j=1..NI)
static constexpr int OF_FCC  = 0;               // 30*33 = 990
static constexpr int OF_FACF = 992;             // 256 vals + 64 scales
static constexpr int OF_FACB = 1312;            // 256 vals + 64 scales
static constexpr int WSB     = 1632;            // per-batch stride

#define LN2F 0.69314718055994530942f
#define NEGF (-1e30f)
#define SBAR() __builtin_amdgcn_sched_barrier(0)

// ---- DPP / cross-lane helpers ------------------------------------------
template<int CTL>
__device__ __forceinline__ float dpp_f(float x, float oldv) {
  return __int_as_float(__builtin_amdgcn_update_dpp(
      __float_as_int(oldv), __float_as_int(x), CTL, 0xF, 0xF, false));
}
template<int M>
__device__ __forceinline__ int rot_i(int x) {
  return __builtin_amdgcn_update_dpp(0, x, 0x120 + M, 0xF, 0xF, false); // row_ror:M
}

typedef unsigned uint2v __attribute__((ext_vector_type(2)));
__device__ __forceinline__ float xsum16(float x) {  // x[l] + x[l^16]
  uint2v r = __builtin_amdgcn_permlane16_swap(__float_as_uint(x), __float_as_uint(x), false, false);
  return __uint_as_float(r.x) + __uint_as_float(r.y);
}
__device__ __forceinline__ float xsum32(float x) {  // x[l] + x[l^32]
  uint2v r = __builtin_amdgcn_permlane32_swap(__float_as_uint(x), __float_as_uint(x), false, false);
  return __uint_as_float(r.x) + __uint_as_float(r.y);
}
__device__ __forceinline__ float bperm(int addr, float src) {  // pull lane addr>>2
  return __int_as_float(__builtin_amdgcn_ds_bpermute(addr, __float_as_int(src)));
}

// Self-calibrating coefficient load (rot_i matches row_ror:M exactly)
template<int M>
struct Calib {
  __device__ static __forceinline__ void run(const float* trans, int lam, int i, float* Ec) {
    Ec[M] = __expf(trans[i * LL + rot_i<M>(lam)]);
    Calib<M + 1>::run(trans, lam, i, Ec);
  }
};
template<> struct Calib<16> {
  __device__ static __forceinline__ void run(const float*, int, int, float*) {}
};
// Transposed variant: coefficient trans[rot(lam)][i]  (M^T matvec)
template<int M>
struct CalibT {
  __device__ static __forceinline__ void run(const float* trans, int lam, int i, float* Ec) {
    Ec[M] = __expf(trans[rot_i<M>(lam) * LL + i]);
    CalibT<M + 1>::run(trans, lam, i, Ec);
  }
};
template<> struct CalibT<16> {
  __device__ static __forceinline__ void run(const float*, int, int, float*) {}
};

// ---- fused rotate-multiply asm (1 instr per term) -----------------------
#define ROT_MUL(DST, SRC, COEF, ROT) \
  asm("v_mul_f32_dpp %0, %1, %2 row_ror:" #ROT " row_mask:0xf bank_mask:0xf" \
      : "=v"(DST) : "v"(SRC), "v"(COEF))
#define ROT_FMAC(ACC, SRC, COEF, ROT) \
  asm("v_fmac_f32_dpp %0, %1, %2 row_ror:" #ROT " row_mask:0xf bank_mask:0xf" \
      : "+v"(ACC) : "v"(SRC), "v"(COEF))

// matvec over 16-lane rows: 8 indep chains of depth 2, then 3-level tree
#define STEP16(EC) { \
  float a0 = EC[0] * A, a1, a2, a3, a4, a5, a6, a7; \
  ROT_MUL(a1, A, EC[1], 1); ROT_MUL(a2, A, EC[2], 2); ROT_MUL(a3, A, EC[3], 3); \
  ROT_MUL(a4, A, EC[4], 4); ROT_MUL(a5, A, EC[5], 5); ROT_MUL(a6, A, EC[6], 6); \
  ROT_MUL(a7, A, EC[7], 7); \
  ROT_FMAC(a0, A, EC[8], 8);   ROT_FMAC(a1, A, EC[9], 9); \
  ROT_FMAC(a2, A, EC[10], 10); ROT_FMAC(a3, A, EC[11], 11); \
  ROT_FMAC(a4, A, EC[12], 12); ROT_FMAC(a5, A, EC[13], 13); \
  ROT_FMAC(a6, A, EC[14], 14); ROT_FMAC(a7, A, EC[15], 15); \
  part = ((a0 + a1) + (a2 + a3)) + ((a4 + a5) + (a6 + a7)); }

// ======================= FCC (self-feeding, register staging) ============

#define FCC_RENORM() { \
  unsigned uu = (unsigned)__builtin_amdgcn_readfirstlane((int)__float_as_uint(A)); \
  int ex = (int)((uu >> 23) & 255) - 127; \
  A = ldexpf(A, -ex); Kt += ex; }

// coalesced loads of rows t..t+7 (2 rows/instr via rowoff); clamp high
#define LDBLK(R, TBASE) { \
  _Pragma("unroll") for (int k = 0; k < 4; ++k) { \
    int tt = (TBASE) + 2 * k + rowoff; tt = tt > lenm1 ? lenm1 : tt; \
    R[k] = gpl[(size_t)tt * STRIDE_T]; } \
  SBAR(); }
// descending variant: clamp both ends
#define LDBLKD(R, TBASE) { \
  _Pragma("unroll") for (int k = 0; k < 4; ++k) { \
    int tt = (TBASE) + 2 * k + rowoff; \
    tt = tt < 0 ? 0 : (tt > lenm1 ? lenm1 : tt); \
    R[k] = gpl[(size_t)tt * STRIDE_T]; } \
  SBAR(); }

#define FCC_BLOCK8(R) { \
  float eb[8]; \
  _Pragma("unroll") for (int k = 0; k < 4; ++k) { \
    float e_ = __expf(R[k]); \
    eb[2 * k]     = bperm(adE, e_); \
    eb[2 * k + 1] = bperm(adO, e_); } \
  { float part; STEP16(Ec1); A = eb[0] * xsum16(part); } \
  { float part; STEP16(Ec2); A = eb[1] * xsum32(part); } \
  { float part; STEP16(Ec1); A = eb[2] * xsum16(part); } \
  { float part; STEP16(Ec2); A = eb[3] * xsum32(part); } \
  { float part; STEP16(Ec1); A = eb[4] * xsum16(part); } \
  { float part; STEP16(Ec2); A = eb[5] * xsum32(part); } \
  { float part; STEP16(Ec1); A = eb[6] * xsum16(part); } \
  { float part; STEP16(Ec2); A = eb[7] * xsum32(part); } \
  FCC_RENORM(); }

// backward (transpose): consumes rows 7..0; emission multiplies BEFORE matvec
#define FCC_BWDBLK8(R) { \
  float eb[8]; \
  _Pragma("unroll") for (int k = 0; k < 4; ++k) { \
    float e_ = __expf(R[k]); \
    eb[2 * k]     = bperm(adE, e_); \
    eb[2 * k + 1] = bperm(adO, e_); } \
  { A *= eb[7]; float part; STEP16(E1T); A = xsum16(part); } \
  { A *= eb[6]; float part; STEP16(E2T); A = xsum32(part); } \
  { A *= eb[5]; float part; STEP16(E1T); A = xsum16(part); } \
  { A *= eb[4]; float part; STEP16(E2T); A = xsum32(part); } \
  { A *= eb[3]; float part; STEP16(E1T); A = xsum16(part); } \
  { A *= eb[2]; float part; STEP16(E2T); A = xsum32(part); } \
  { A *= eb[1]; float part; STEP16(E1T); A = xsum16(part); } \
  { A *= eb[0]; float part; STEP16(E2T); A = xsum32(part); } \
  FCC_RENORM(); }

// ======================= FAC (self-feeding, register gather) =============

#define FAC_BOUNDARY() { \
  float maxA = fmaxf(fmaxf(A0, A1), fmaxf(A2, A3)); \
  if (maxA > 0.f) { \
    int ex = (int)((__float_as_uint(maxA) >> 23) & 255) - 127; \
    A0 = ldexpf(A0, -ex); A1 = ldexpf(A1, -ex); \
    A2 = ldexpf(A2, -ex); A3 = ldexpf(A3, -ex); \
    m += (float)ex; \
  } \
  float mp = dpp_f<0x138>(m, NEGF); m = (m == NEGF) ? mp : m; \
  mp = dpp_f<0x138>(m, NEGF);       m = (m == NEGF) ? mp : m; \
  mp = dpp_f<0x138>(m, NEGF); \
  float dlt = fminf(mp - m, 50.0f); \
  float Sin = exp2f(dlt); \
  MV0b = MVl[0] * Sin; }

#define FACB_BOUNDARY() { \
  float maxA = fmaxf(fmaxf(A0, A1), fmaxf(A2, A3)); \
  if (maxA > 0.f) { \
    int ex = (int)((__float_as_uint(maxA) >> 23) & 255) - 127; \
    A0 = ldexpf(A0, -ex); A1 = ldexpf(A1, -ex); \
    A2 = ldexpf(A2, -ex); A3 = ldexpf(A3, -ex); \
    m += (float)ex; \
  } \
  float mp = dpp_f<0x130>(m, NEGF); m = (m == NEGF) ? mp : m; \
  mp = dpp_f<0x130>(m, NEGF);       m = (m == NEGF) ? mp : m; \
  mp = dpp_f<0x130>(m, NEGF); \
  float dlt = fminf(mp - m, 50.0f); \
  MVn3b = MVn[3] * exp2f(dlt); }

// one fwd step from a gathered float4
#define FSTEP1(EE) { \
  float ap = dpp_f<0x138>(A3, 0.f); /* wave_shr:1 */ \
  float n0 = (EE).x * fmaf(MV0b,  ap, ST[0] * A0); \
  float n1 = (EE).y * fmaf(MVl[1], A0, ST[1] * A1); \
  float n2 = (EE).z * fmaf(MVl[2], A1, ST[2] * A2); \
  float n3 = (EE).w * fmaf(MVl[3], A2, ST[3] * A3); \
  A0 = n0; A1 = n1; A2 = n2; A3 = n3; }

// one bwd step from a gathered float4
#define BSTEP1(EE) { \
  float en3 = dpp_f<0x130>((EE).x, 0.f); /* wave_shl:1 */ \
  float an  = dpp_f<0x130>(A0, 0.f); \
  float n0 = fmaf((EE).y * MVn[0], A1, (EE).x * ST[0] * A0); \
  float n1 = fmaf((EE).z * MVn[1], A2, (EE).y * ST[1] * A1); \
  float n2 = fmaf((EE).w * MVn[2], A3, (EE).z * ST[2] * A2); \
  float n3 = fmaf(en3 * MVn3b,      an, (EE).w * ST[3] * A3); \
  A0 = n0; A1 = n1; A2 = n2; A3 = n3; }

// gather 8 rows of E from 4 loaded values (exp before gather: identical)
#define GATH(E, Q) { \
  _Pragma("unroll") for (int k = 0; k < 4; ++k) { \
    float e_ = __expf(Q[k]); \
    E[2 * k].x = bperm(adA[0], e_); E[2 * k].y = bperm(adA[1], e_); \
    E[2 * k].z = bperm(adA[2], e_); E[2 * k].w = bperm(adA[3], e_); \
    E[2 * k + 1].x = bperm(adB[0], e_); E[2 * k + 1].y = bperm(adB[1], e_); \
    E[2 * k + 1].z = bperm(adB[2], e_); E[2 * k + 1].w = bperm(adB[3], e_); } }

#define FSTEP8(E) { FSTEP1(E[0]); FSTEP1(E[1]); FSTEP1(E[2]); FSTEP1(E[3]); \
                    FSTEP1(E[4]); FSTEP1(E[5]); FSTEP1(E[6]); FSTEP1(E[7]); \
                    FAC_BOUNDARY(); }
#define FTAILF(E, CNT) { \
  _Pragma("unroll") for (int r = 0; r < 8; ++r) { \
    if (r >= (CNT)) break; FSTEP1(E[r]); } }
#define BSTEP8(E) { BSTEP1(E[7]); BSTEP1(E[6]); BSTEP1(E[5]); BSTEP1(E[4]); \
                    BSTEP1(E[3]); BSTEP1(E[2]); BSTEP1(E[1]); BSTEP1(E[0]); \
                    FACB_BOUNDARY(); }

// FAC load macros (group G of 8 rows, pair K)
#define FLD(G, K) ({ \
  int tt_ = 1 + 8 * (G) + 2 * (K) + rowoff; \
  tt_ = tt_ > lenm1 ? lenm1 : tt_; \
  gpl[(size_t)tt_ * STRIDE_T]; })
#define BLD(G, K) ({ \
  int tt_ = lenm1 - 8 * (G) - 7 + 2 * (K) + rowoff; \
  tt_ = tt_ < 0 ? 0 : (tt_ > lenm1 ? lenm1 : tt_); \
  gpl[(size_t)tt_ * STRIDE_T]; })

#define ROTQF(G) { \
  _Pragma("unroll") for (int k = 0; k < 4; ++k) { \
    Q1[k] = Q2[k]; Q2[k] = Q3[k]; Q3[k] = FLD(G, k); } SBAR(); }
#define ROTQB(G) { \
  _Pragma("unroll") for (int k = 0; k < 4; ++k) { \
    Q1[k] = Q2[k]; Q2[k] = Q3[k]; Q3[k] = BLD(G, k); } SBAR(); }

// ======================= main kernel ====================================
// grid: [0,128)        = FAC halves (1 wave each)
//       [128,128+30*64)= FCC chunk scans (1 wave each)

extern "C" __global__ __launch_bounds__(64, 1)
void asg_main(const float* __restrict__ trans, const float* __restrict__ inputs,
              const int* __restrict__ targets, const int* __restrict__ ilen,
              const int* __restrict__ tlen, float* __restrict__ ws) {
  const int l = threadIdx.x;
  const int lam1 = l & 31;
  const int lam2 = (l & 15) | ((l >> 5) << 4);
  const int rowoff = l >> 5;
  const int bid = (int)blockIdx.x;

  if (bid < 2 * TB) {
    // ================= FAC halves (self-feeding) ======================
    const int role = bid >> 6;   // 0 fwd, 1 bwd
    const int b    = bid & 63;
    const int len = ilen[b];
    const int lenm1 = len - 1;
    const int Lsteps = lenm1;
    const int nbf = (Lsteps / 2) & ~7;   // bwd steps (mult of 8, no tail)
    const int nff = Lsteps - nbf;        // fwd steps (tail ok)
    const float* gpl = inputs + (size_t)b * LL + lam1;
    float* P = ws + (size_t)b * WSB;

    int tg[4];
    #pragma unroll
    for (int q = 0; q < 4; ++q) tg[q] = targets[b * SS + 4 * l + q];
    float ST[4];
    #pragma unroll
    for (int q = 0; q < 4; ++q) ST[q] = __expf(trans[tg[q] * LL + tg[q]]);
    int adA[4], adB[4];
    #pragma unroll
    for (int j = 0; j < 4; ++j) { adA[j] = tg[j] * 4; adB[j] = adA[j] + 128; }

    if (role == 0) {
      // ---- forward half ----
      float MVl[4];
      MVl[0] = (l == 0) ? 0.f : __expf(trans[tg[0] * LL + targets[b * SS + 4 * l - 1]]);
      #pragma unroll
      for (int q = 1; q < 4; ++q) MVl[q] = __expf(trans[tg[q] * LL + tg[q - 1]]);

      float A0 = (l == 0) ? __expf(inputs[(size_t)b * LL + tg[0]]) : 0.f;
      float A1 = 0.f, A2 = 0.f, A3 = 0.f;
      float m  = (l == 0) ? 0.f : NEGF;
      float MV0b;
      FAC_BOUNDARY();

      const int nsteps = nff;
      const int ngrp = (nsteps + 7) >> 3;
      float Q1[4], Q2[4], Q3[4];
      #pragma unroll
      for (int k = 0; k < 4; ++k) Q1[k] = FLD(0, k);
      #pragma unroll
      for (int k = 0; k < 4; ++k) Q2[k] = FLD(1, k);
      #pragma unroll
      for (int k = 0; k < 4; ++k) Q3[k] = FLD(2, k);
      float4 Ea[8], Eb[8];
      GATH(Ea, Q1);
      ROTQF(3);
      for (int g = 0; g < ngrp; g += 2) {
        if (g + 1 < ngrp) { GATH(Eb, Q1); ROTQF(g + 4); }
        { const int rem = nsteps - 8 * g;
          if (rem >= 8) { FSTEP8(Ea); } else { FTAILF(Ea, rem); } }
        if (g + 1 >= ngrp) break;
        if (g + 2 < ngrp) { GATH(Ea, Q1); ROTQF(g + 5); }
        { const int rem = nsteps - 8 * (g + 1);
          if (rem >= 8) { FSTEP8(Eb); } else { FTAILF(Eb, rem); } }
      }
      P[OF_FACF + 4 * l + 0] = A0;
      P[OF_FACF + 4 * l + 1] = A1;
      P[OF_FACF + 4 * l + 2] = A2;
      P[OF_FACF + 4 * l + 3] = A3;
      P[OF_FACF + 256 + l]   = m;

    } else {
      // ---- backward half (beta) ----
      float MVn[4];
      MVn[0] = __expf(trans[tg[1] * LL + tg[0]]);
      MVn[1] = __expf(trans[tg[2] * LL + tg[1]]);
      MVn[2] = __expf(trans[tg[3] * LL + tg[2]]);
      int tgn3 = (l < 63) ? targets[b * SS + 4 * l + 4] : 0;
      MVn[3] = (l < 63) ? __expf(trans[tgn3 * LL + tg[3]]) : 0.f;

      const int tl = tlen[b];
      const int fs = tl - 1;
      float A0 = (4 * l + 0 == fs) ? 1.f : 0.f;
      float A1 = (4 * l + 1 == fs) ? 1.f : 0.f;
      float A2 = (4 * l + 2 == fs) ? 1.f : 0.f;
      float A3 = (4 * l + 3 == fs) ? 1.f : 0.f;
      float m  = (l == (fs >> 2)) ? 0.f : NEGF;
      float MVn3b;
      FACB_BOUNDARY();

      const int ngrp = nbf >> 3;           // no tail
      float Q1[4], Q2[4], Q3[4];
      #pragma unroll
      for (int k = 0; k < 4; ++k) Q1[k] = BLD(0, k);
      #pragma unroll
      for (int k = 0; k < 4; ++k) Q2[k] = BLD(1, k);
      #pragma unroll
      for (int k = 0; k < 4; ++k) Q3[k] = BLD(2, k);
      float4 Ea[8], Eb[8];
      GATH(Ea, Q1);
      ROTQB(3);
      for (int g = 0; g < ngrp; g += 2) {
        if (g + 1 < ngrp) { GATH(Eb, Q1); ROTQB(g + 4); }
        BSTEP8(Ea);
        if (g + 1 >= ngrp) break;
        if (g + 2 < ngrp) { GATH(Ea, Q1); ROTQB(g + 5); }
        BSTEP8(Eb);
      }
      P[OF_FACB + 4 * l + 0] = A0;
      P[OF_FACB + 4 * l + 1] = A1;
      P[OF_FACB + 4 * l + 2] = A2;
      P[OF_FACB + 4 * l + 3] = A3;
      P[OF_FACB + 256 + l]   = m;
    }
    return;
  }

  // ================= FCC chunk scans (self-feeding) ====================
  const int cid = bid - 2 * TB;
  const int s = cid >> 6;          // scan id 0..NSCAN-1
  const int b = cid & 63;
  const int len = ilen[b];
  const int lenm1 = len - 1;
  const int Lsteps = lenm1;
  int L = ((Lsteps / NCH) + 4) & ~7;           // balanced chunk length
  if ((NCH - 1) * L > Lsteps) L = (Lsteps / NCH) & ~7;
  const int n0 = Lsteps - (NCH - 1) * L;       // chunk0 length (has tail)

  bool isfwd; int t0 = 1, thi = lenm1, nsteps, outslot;
  if (s == 0)      { isfwd = true;  t0 = 1; nsteps = n0; outslot = 0; }
  else if (s == 1) { isfwd = false; thi = lenm1; nsteps = L; outslot = 1; }
  else {
    const int j = s >> 1;                      // 1..NI
    if ((s & 1) == 0) { isfwd = true;  t0 = n0 + (j - 1) * L + 1; nsteps = L; outslot = 2 * j; }
    else              { isfwd = false; thi = n0 + j * L;          nsteps = L; outslot = 2 * j + 1; }
  }
  const float* gpl = inputs + (size_t)b * LL + lam1;
  float* P = ws + (size_t)b * WSB + OF_FCC + outslot * 33;

  const int adE = lam2 * 4;         // even step gather addr
  const int adO = 128 + lam1 * 4;   // odd step gather addr

  if (isfwd) {
    float Ec1[16], Ec2[16];
    Ec1[0] = __expf(trans[lam2 * LL + lam1]);
    Ec2[0] = __expf(trans[lam1 * LL + lam2]);
    Calib<1>::run(trans, lam1, lam2, Ec1);
    Calib<1>::run(trans, lam2, lam1, Ec2);
    float A = (s == 0) ? __expf(inputs[(size_t)b * LL + lam1]) : 1.f;
    int Kt = 0;
    int t = t0;
    const int tend = t0 + nsteps;
    float R0_[4], R1_[4], R2_[4];
    LDBLK(R0_, t); LDBLK(R1_, t + 8); LDBLK(R2_, t + 16);
    for (;;) {
      if (t + 8 > tend) break;
      FCC_BLOCK8(R0_); LDBLK(R0_, t + 24); t += 8;
      if (t + 8 > tend) break;
      FCC_BLOCK8(R1_); LDBLK(R1_, t + 24); t += 8;
      if (t + 8 > tend) break;
      FCC_BLOCK8(R2_); LDBLK(R2_, t + 24); t += 8;
    }
    if (t < tend) {  // tail (<8 steps)
      float RT[4];
      LDBLK(RT, t);
      float eb[8];
      #pragma unroll
      for (int k = 0; k < 4; ++k) {
        float e_ = __expf(RT[k]);
        eb[2 * k]     = bperm(adE, e_);
        eb[2 * k + 1] = bperm(adO, e_);
      }
      #pragma unroll
      for (int q = 0; q < 8; ++q) {
        if (t + q >= tend) break;
        if ((q & 1) == 0) { float part; STEP16(Ec1); A = eb[q] * xsum16(part); }
        else              { float part; STEP16(Ec2); A = eb[q] * xsum32(part); }
      }
    }
    const int par = nsteps & 1;
    const int idx = par ? lam2 : lam1;
    const bool wr = par ? ((l & 16) == 0) : (l < 32);
    if (wr) P[idx] = A;
    if (l == 0) P[32] = (float)Kt;

  } else {
    float E1T[16], E2T[16];
    E1T[0] = __expf(trans[lam1 * LL + lam2]);
    E2T[0] = __expf(trans[lam2 * LL + lam1]);
    CalibT<1>::run(trans, lam1, lam2, E1T);
    CalibT<1>::run(trans, lam2, lam1, E2T);
    float A = 1.f;
    int Kt = 0;
    int th = thi;
    int rem = nsteps;               // multiple of 8
    float R0_[4], R1_[4], R2_[4];
    LDBLKD(R0_, th - 7); LDBLKD(R1_, th - 15); LDBLKD(R2_, th - 23);
    for (;;) {
      if (rem < 8) break;
      FCC_BWDBLK8(R0_); LDBLKD(R0_, th - 31); th -= 8; rem -= 8;
      if (rem < 8) break;
      FCC_BWDBLK8(R1_); LDBLKD(R1_, th - 31); th -= 8; rem -= 8;
      if (rem < 8) break;
      FCC_BWDBLK8(R2_); LDBLKD(R2_, th - 31); th -= 8; rem -= 8;
    }
    if (l < 32) P[lam1] = A;        // L even -> lam1 layout
    if (l == 0) P[32] = (float)Kt;
  }
}

// ======================= combine ========================================

extern "C" __global__ __launch_bounds__(1024)
void asg_combine(const float* __restrict__ ws, float* __restrict__ out) {
  __shared__ float sd[TB];
  const int tid = (int)threadIdx.x;
  const int w = tid >> 6, l = tid & 63;

  for (int k = 0; k < 4; ++k) {
    const int b = w * 4 + k;
    const float* P = ws + (size_t)b * WSB;

    // ---- FCC: telescoped rank-1 chunk products ----
    float acc = 0.f;
    float Ksum = P[OF_FCC + 0 * 33 + 32];           // Ka
    for (int j = 0; j <= NI; ++j) {
      const int qs = (j == NI) ? 1 : (2 * j + 3);   // q_{j+1}, last = c
      const int ps = (j == 0) ? 0 : (2 * j);        // p_j, first = a
      float qv = (l < 32) ? P[OF_FCC + qs * 33 + l] : 0.f;
      float pv = (l < 32) ? P[OF_FCC + ps * 33 + l] : 0.f;
      float d = qv * pv;
      #pragma unroll
      for (int mm = 1; mm < 64; mm <<= 1) d += __shfl_xor(d, mm);
      acc += __logf(d);
      Ksum += P[OF_FCC + qs * 33 + 32];             // Kq (or Kc)
    }
    for (int j = 1; j <= NI; ++j) {
      float pv = (l < 32) ? P[OF_FCC + 2 * j * 33 + l] : 0.f;
      #pragma unroll
      for (int mm = 1; mm < 64; mm <<= 1) pv += __shfl_xor(pv, mm);
      acc -= __logf(pv);
    }
    float fcc = acc + Ksum * LN2F;

    // ---- FAC: score = sum_s alpha[s] * beta[s] ----
    float pa = P[OF_FACF + 4 * l + 0] * P[OF_FACB + 4 * l + 0]
             + P[OF_FACF + 4 * l + 1] * P[OF_FACB + 4 * l + 1]
             + P[OF_FACF + 4 * l + 2] * P[OF_FACB + 4 * l + 2]
             + P[OF_FACF + 4 * l + 3] * P[OF_FACB + 4 * l + 3];
    float sc = P[OF_FACF + 256 + l] + P[OF_FACB + 256 + l];
    float Ms = sc;
    #pragma unroll
    for (int mm = 1; mm < 64; mm <<= 1) Ms = fmaxf(Ms, __shfl_xor(Ms, mm));
    float pp = pa * exp2f(sc - Ms);
    #pragma unroll
    for (int mm = 1; mm < 64; mm <<= 1) pp += __shfl_xor(pp, mm);
    float fac = __logf(pp) + Ms * LN2F;

    if (l == 0) sd[b] = fcc - fac;
  }
  __syncthreads();
  if (tid < TB) {
    float d = sd[tid];
    #pragma unroll
    for (int mm = 1; mm < 64; mm <<= 1) d += __shfl_xor(d, mm);
    if (tid == 0) out[0] = d * (1.0f / TB);
  }
}

// ======================= launcher =======================================

extern "C" void kernel_launch(void* const* d_in, const int* in_sizes, int n_in,
                              void* d_out, int out_size, void* d_ws, size_t ws_size,
                              hipStream_t stream) {
  const float* trans   = (const float*)d_in[0];
  const float* inputs  = (const float*)d_in[1];
  const int*   targets = (const int*)d_in[2];
  const int*   ilen    = (const int*)d_in[3];
  const int*   tlen    = (const int*)d_in[4];
  float* out = (float*)d_out;
  float* ws  = (float*)d_ws;

  // 128 FAC waves + 30*64 FCC chunk-scan waves, all single-wave blocks
  asg_main<<<dim3(2 * TB + NSCAN * TB), dim3(64), 0, stream>>>(
      trans, inputs, targets, ilen, tlen, ws);
  asg_combine<<<dim3(1), dim3(1024), 0, stream>>>(ws, out);
}

// Round 8
// 115.945 us; speedup vs baseline: 1.4694x; 1.4694x over previous
//
#include <hip/hip_runtime.h>
#include <math.h>

static constexpr int TB = 64;   // batch
static constexpr int LL = 32;   // labels
static constexpr int SS = 256;  // max target length
static constexpr int STRIDE_T = TB * LL;  // floats per time step (2048)

// FCC chunking: NCH chunks -> chunk0 (fwd, init), NI interior (fwd+bwd), last (bwd)
static constexpr int NCH = 16;
static constexpr int NI  = NCH - 2;             // 14 interior
static constexpr int NSCAN = 2 + 2 * NI;        // 30 scans per batch

// ---- workspace layout (floats per batch) --------------------------------
// FCC slots (33 floats): 0=a, 1=c, 2j=p_j, 2j+1=q_j (j=1..NI)
static constexpr int OF_FCC  = 0;               // 30*33 = 990
static constexpr int OF_FACF = 992;             // 256 vals + 64 scales
static constexpr int OF_FACB = 1312;            // 256 vals + 64 scales
static constexpr int WSB     = 1632;            // per-batch stride

#define LN2F 0.69314718055994530942f
#define NEGF (-1e30f)
#define SBAR() __builtin_amdgcn_sched_barrier(0)

// raw barrier: waits LDS only (keeps global-load prefetch in flight)
#define BARX() { asm volatile("s_waitcnt lgkmcnt(0)" ::: "memory"); \
                 __builtin_amdgcn_s_barrier(); \
                 asm volatile("" ::: "memory"); }

// ---- DPP / cross-lane helpers ------------------------------------------
template<int CTL>
__device__ __forceinline__ float dpp_f(float x, float oldv) {
  return __int_as_float(__builtin_amdgcn_update_dpp(
      __float_as_int(oldv), __float_as_int(x), CTL, 0xF, 0xF, false));
}
template<int M>
__device__ __forceinline__ int rot_i(int x) {
  return __builtin_amdgcn_update_dpp(0, x, 0x120 + M, 0xF, 0xF, false); // row_ror:M
}

typedef unsigned uint2v __attribute__((ext_vector_type(2)));
__device__ __forceinline__ float xsum16(float x) {  // x[l] + x[l^16]
  uint2v r = __builtin_amdgcn_permlane16_swap(__float_as_uint(x), __float_as_uint(x), false, false);
  return __uint_as_float(r.x) + __uint_as_float(r.y);
}
__device__ __forceinline__ float xsum32(float x) {  // x[l] + x[l^32]
  uint2v r = __builtin_amdgcn_permlane32_swap(__float_as_uint(x), __float_as_uint(x), false, false);
  return __uint_as_float(r.x) + __uint_as_float(r.y);
}
__device__ __forceinline__ float bperm(int addr, float src) {  // pull lane addr>>2
  return __int_as_float(__builtin_amdgcn_ds_bpermute(addr, __float_as_int(src)));
}

// Self-calibrating coefficient load (rot_i matches row_ror:M exactly)
template<int M>
struct Calib {
  __device__ static __forceinline__ void run(const float* trans, int lam, int i, float* Ec) {
    Ec[M] = __expf(trans[i * LL + rot_i<M>(lam)]);
    Calib<M + 1>::run(trans, lam, i, Ec);
  }
};
template<> struct Calib<16> {
  __device__ static __forceinline__ void run(const float*, int, int, float*) {}
};
// Transposed variant: coefficient trans[rot(lam)][i]  (M^T matvec)
template<int M>
struct CalibT {
  __device__ static __forceinline__ void run(const float* trans, int lam, int i, float* Ec) {
    Ec[M] = __expf(trans[rot_i<M>(lam) * LL + i]);
    CalibT<M + 1>::run(trans, lam, i, Ec);
  }
};
template<> struct CalibT<16> {
  __device__ static __forceinline__ void run(const float*, int, int, float*) {}
};

// ---- fused rotate-multiply asm (1 instr per term) -----------------------
#define ROT_MUL(DST, SRC, COEF, ROT) \
  asm("v_mul_f32_dpp %0, %1, %2 row_ror:" #ROT " row_mask:0xf bank_mask:0xf" \
      : "=v"(DST) : "v"(SRC), "v"(COEF))
#define ROT_FMAC(ACC, SRC, COEF, ROT) \
  asm("v_fmac_f32_dpp %0, %1, %2 row_ror:" #ROT " row_mask:0xf bank_mask:0xf" \
      : "+v"(ACC) : "v"(SRC), "v"(COEF))

// matvec over 16-lane rows: 8 indep chains of depth 2, then 3-level tree
#define STEP16(EC) { \
  float a0 = EC[0] * A, a1, a2, a3, a4, a5, a6, a7; \
  ROT_MUL(a1, A, EC[1], 1); ROT_MUL(a2, A, EC[2], 2); ROT_MUL(a3, A, EC[3], 3); \
  ROT_MUL(a4, A, EC[4], 4); ROT_MUL(a5, A, EC[5], 5); ROT_MUL(a6, A, EC[6], 6); \
  ROT_MUL(a7, A, EC[7], 7); \
  ROT_FMAC(a0, A, EC[8], 8);   ROT_FMAC(a1, A, EC[9], 9); \
  ROT_FMAC(a2, A, EC[10], 10); ROT_FMAC(a3, A, EC[11], 11); \
  ROT_FMAC(a4, A, EC[12], 12); ROT_FMAC(a5, A, EC[13], 13); \
  ROT_FMAC(a6, A, EC[14], 14); ROT_FMAC(a7, A, EC[15], 15); \
  part = ((a0 + a1) + (a2 + a3)) + ((a4 + a5) + (a6 + a7)); }

// ======================= FCC (self-feeding, register staging) ============

#define FCC_RENORM() { \
  unsigned uu = (unsigned)__builtin_amdgcn_readfirstlane((int)__float_as_uint(A)); \
  int ex = (int)((uu >> 23) & 255) - 127; \
  A = ldexpf(A, -ex); Kt += ex; }

// coalesced loads of rows t..t+7 (2 rows/instr via rowoff); clamp high
#define LDBLK(R, TBASE) { \
  _Pragma("unroll") for (int k = 0; k < 4; ++k) { \
    int tt = (TBASE) + 2 * k + rowoff; tt = tt > lenm1 ? lenm1 : tt; \
    R[k] = gpl[(size_t)tt * STRIDE_T]; } \
  SBAR(); }
// descending variant: clamp both ends
#define LDBLKD(R, TBASE) { \
  _Pragma("unroll") for (int k = 0; k < 4; ++k) { \
    int tt = (TBASE) + 2 * k + rowoff; \
    tt = tt < 0 ? 0 : (tt > lenm1 ? lenm1 : tt); \
    R[k] = gpl[(size_t)tt * STRIDE_T]; } \
  SBAR(); }

#define FCC_BLOCK8(R) { \
  float eb[8]; \
  _Pragma("unroll") for (int k = 0; k < 4; ++k) { \
    float e_ = __expf(R[k]); \
    eb[2 * k]     = bperm(adE, e_); \
    eb[2 * k + 1] = bperm(adO, e_); } \
  { float part; STEP16(Ec1); A = eb[0] * xsum16(part); } \
  { float part; STEP16(Ec2); A = eb[1] * xsum32(part); } \
  { float part; STEP16(Ec1); A = eb[2] * xsum16(part); } \
  { float part; STEP16(Ec2); A = eb[3] * xsum32(part); } \
  { float part; STEP16(Ec1); A = eb[4] * xsum16(part); } \
  { float part; STEP16(Ec2); A = eb[5] * xsum32(part); } \
  { float part; STEP16(Ec1); A = eb[6] * xsum16(part); } \
  { float part; STEP16(Ec2); A = eb[7] * xsum32(part); } \
  FCC_RENORM(); }

// backward (transpose): consumes rows 7..0; emission multiplies BEFORE matvec
#define FCC_BWDBLK8(R) { \
  float eb[8]; \
  _Pragma("unroll") for (int k = 0; k < 4; ++k) { \
    float e_ = __expf(R[k]); \
    eb[2 * k]     = bperm(adE, e_); \
    eb[2 * k + 1] = bperm(adO, e_); } \
  { A *= eb[7]; float part; STEP16(E1T); A = xsum16(part); } \
  { A *= eb[6]; float part; STEP16(E2T); A = xsum32(part); } \
  { A *= eb[5]; float part; STEP16(E1T); A = xsum16(part); } \
  { A *= eb[4]; float part; STEP16(E2T); A = xsum32(part); } \
  { A *= eb[3]; float part; STEP16(E1T); A = xsum16(part); } \
  { A *= eb[2]; float part; STEP16(E2T); A = xsum32(part); } \
  { A *= eb[1]; float part; STEP16(E1T); A = xsum16(part); } \
  { A *= eb[0]; float part; STEP16(E2T); A = xsum32(part); } \
  FCC_RENORM(); }

// ======================= FAC (E-only LDS staging, 32-step phases) =======
// sFE[.][r][l] = {E[tg0],E[tg1],E[tg2],E[tg3]} gathered for lane l at row r.

#define FAC_BOUNDARY_S() { \
  float maxA = fmaxf(fmaxf(A0, A1), fmaxf(A2, A3)); \
  if (maxA > 0.f) { \
    int ex = (int)((__float_as_uint(maxA) >> 23) & 255) - 127; \
    A0 = ldexpf(A0, -ex); A1 = ldexpf(A1, -ex); \
    A2 = ldexpf(A2, -ex); A3 = ldexpf(A3, -ex); \
    m += (float)ex; \
  } \
  float mp = dpp_f<0x138>(m, NEGF); m = (m == NEGF) ? mp : m; \
  mp = dpp_f<0x138>(m, NEGF);       m = (m == NEGF) ? mp : m; \
  mp = dpp_f<0x138>(m, NEGF); \
  float dlt = fminf(mp - m, 50.0f); \
  Sin = exp2f(dlt); }

#define FSTEPE(R) { \
  float c0 = Er[R].x * ST[0], c1 = Er[R].y * ST[1]; \
  float c2 = Er[R].z * ST[2], c3 = Er[R].w * ST[3]; \
  float v0 = Er[R].x * CM[0], v1 = Er[R].y * CM[1]; \
  float v2 = Er[R].z * CM[2], v3 = Er[R].w * CM[3]; \
  float ap = dpp_f<0x138>(A3, 0.f); /* wave_shr:1 */ \
  float n0 = fmaf(v0 * Sin, ap, c0 * A0); \
  float n1 = fmaf(v1, A0, c1 * A1); \
  float n2 = fmaf(v2, A1, c2 * A2); \
  float n3 = fmaf(v3, A2, c3 * A3); \
  A0 = n0; A1 = n1; A2 = n2; A3 = n3; }

#define FRD16(PB, BASE) { \
  _Pragma("unroll") for (int r = 0; r < 16; ++r) Er[r] = sFE[PB][(BASE) + r][l]; }

#define FSTE8A() { FSTEPE(0); FSTEPE(1); FSTEPE(2); FSTEPE(3); \
                   FSTEPE(4); FSTEPE(5); FSTEPE(6); FSTEPE(7); }
#define FSTE8B() { FSTEPE(8); FSTEPE(9); FSTEPE(10); FSTEPE(11); \
                   FSTEPE(12); FSTEPE(13); FSTEPE(14); FSTEPE(15); }

#define FACF_CON32(PB) { \
  float4 Er[16]; \
  FRD16(PB, 0); \
  FSTE8A(); FAC_BOUNDARY_S(); \
  FSTE8B(); FAC_BOUNDARY_S(); \
  FRD16(PB, 16); \
  FSTE8A(); FAC_BOUNDARY_S(); \
  FSTE8B(); FAC_BOUNDARY_S(); }

#define FACF_TAIL32(PB, CNT) { \
  float4 Er[16]; \
  FRD16(PB, 0); \
  _Pragma("unroll") for (int r = 0; r < 16; ++r) { \
    if (r >= (CNT)) break; \
    FSTEPE(r); \
    if (r == 7) { FAC_BOUNDARY_S(); } } \
  if ((CNT) > 16) { \
    FAC_BOUNDARY_S(); \
    FRD16(PB, 16); \
    _Pragma("unroll") for (int r = 0; r < 16; ++r) { \
      if (r + 16 >= (CNT)) break; \
      FSTEPE(r); \
      if (r == 7) { FAC_BOUNDARY_S(); } } } }

#define FACB_BOUNDARY_S() { \
  float maxA = fmaxf(fmaxf(A0, A1), fmaxf(A2, A3)); \
  if (maxA > 0.f) { \
    int ex = (int)((__float_as_uint(maxA) >> 23) & 255) - 127; \
    A0 = ldexpf(A0, -ex); A1 = ldexpf(A1, -ex); \
    A2 = ldexpf(A2, -ex); A3 = ldexpf(A3, -ex); \
    m += (float)ex; \
  } \
  float mp = dpp_f<0x130>(m, NEGF); m = (m == NEGF) ? mp : m; \
  mp = dpp_f<0x130>(m, NEGF);       m = (m == NEGF) ? mp : m; \
  mp = dpp_f<0x130>(m, NEGF); \
  float dlt = fminf(mp - m, 50.0f); \
  Sb = exp2f(dlt); }

#define FBSTEPE(R) { \
  float c0 = Er[R].x * ST[0], c1 = Er[R].y * ST[1]; \
  float c2 = Er[R].z * ST[2], c3 = Er[R].w * ST[3]; \
  float w0 = Er[R].y * CM[0], w1 = Er[R].z * CM[1], w2 = Er[R].w * CM[2]; \
  float en3 = dpp_f<0x130>(Er[R].x, 0.f); /* wave_shl:1 */ \
  float w3 = en3 * CM[3]; \
  float an = dpp_f<0x130>(A0, 0.f); \
  float n0 = fmaf(w0, A1, c0 * A0); \
  float n1 = fmaf(w1, A2, c1 * A1); \
  float n2 = fmaf(w2, A3, c2 * A2); \
  float n3 = fmaf(w3 * Sb, an, c3 * A3); \
  A0 = n0; A1 = n1; A2 = n2; A3 = n3; }

#define FBST8D() { FBSTEPE(15); FBSTEPE(14); FBSTEPE(13); FBSTEPE(12); \
                   FBSTEPE(11); FBSTEPE(10); FBSTEPE(9);  FBSTEPE(8); }
#define FBST8L() { FBSTEPE(7);  FBSTEPE(6);  FBSTEPE(5);  FBSTEPE(4); \
                   FBSTEPE(3);  FBSTEPE(2);  FBSTEPE(1);  FBSTEPE(0); }

#define FACB_CON32(PB) { \
  float4 Er[16]; \
  FRD16(PB, 16); \
  FBST8D(); FACB_BOUNDARY_S(); \
  FBST8L(); FACB_BOUNDARY_S(); \
  FRD16(PB, 0); \
  FBST8D(); FACB_BOUNDARY_S(); \
  FBST8L(); FACB_BOUNDARY_S(); }

// ======================= FAC staging loads ==============================

// 32-row phases: pair K = 0..15
#define FHLD32(Q, K) ({ \
  int tt_ = (isfwd ? (1 + 32 * (Q)) : (lenm1 - 32 * (Q) - 31)) + 2 * (K) + rowoff; \
  tt_ = tt_ < 0 ? 0 : (tt_ > lenm1 ? lenm1 : tt_); \
  gpl[(size_t)tt_ * STRIDE_T]; })

// gather-only produce: one loaded value covers 2 rows (lane halves)
#define PRODE(PB, KK, RV) { \
  float e_ = __expf(RV); \
  float4 E0_, E1_; \
  E0_.x = bperm(adA[0], e_); E0_.y = bperm(adA[1], e_); \
  E0_.z = bperm(adA[2], e_); E0_.w = bperm(adA[3], e_); \
  E1_.x = bperm(adB[0], e_); E1_.y = bperm(adB[1], e_); \
  E1_.z = bperm(adB[2], e_); E1_.w = bperm(adB[3], e_); \
  sFE[PB][2 * (KK)][l]     = E0_; \
  sFE[PB][2 * (KK) + 1][l] = E1_; }

// ======================= main kernel ====================================
// grid: [0,128)     = FAC halves (chain + 2 helpers, 32-step phases)
//       [128,768)   = FCC chunk scans (3 independent self-feeding waves/block)

extern "C" __global__ __launch_bounds__(192, 1)
void asg_main(const float* __restrict__ trans, const float* __restrict__ inputs,
              const int* __restrict__ targets, const int* __restrict__ ilen,
              const int* __restrict__ tlen, float* __restrict__ ws) {
  const int tid = (int)threadIdx.x;
  const int w = tid >> 6;
  const int l = tid & 63;
  const int lam1 = l & 31;
  const int lam2 = (l & 15) | ((l >> 5) << 4);
  const int rowoff = l >> 5;
  const int bid = (int)blockIdx.x;

  __shared__ float4 sFE[2][32][64];  // FAC gathered-E staging (64 KB)

  if (bid < 2 * TB) {
    // ================= FAC halves ====================================
    const int role = bid >> 6;   // 0 fwd, 1 bwd
    const int b    = bid & 63;
    const int len = ilen[b];
    const int lenm1 = len - 1;
    const int Lsteps = lenm1;
    const int nbf = (Lsteps / 2) & ~31;    // bwd steps (mult of 32, no tail)
    const int nff = Lsteps - nbf;          // fwd steps (tail ok)
    const bool isfwd = (role == 0);
    const int nsteps = isfwd ? nff : nbf;
    const int nph = (nsteps + 31) >> 5;
    const float* gpl = inputs + (size_t)b * LL + lam1;
    float* P = ws + (size_t)b * WSB;

    if (w == 0) {
      // ---- chain wave ----
      __builtin_amdgcn_s_setprio(1);
      int tg[4];
      #pragma unroll
      for (int q = 0; q < 4; ++q) tg[q] = targets[b * SS + 4 * l + q];
      float ST[4], CM[4];
      #pragma unroll
      for (int q = 0; q < 4; ++q) ST[q] = __expf(trans[tg[q] * LL + tg[q]]);

      if (isfwd) {
        CM[0] = (l == 0) ? 0.f : __expf(trans[tg[0] * LL + targets[b * SS + 4 * l - 1]]);
        #pragma unroll
        for (int q = 1; q < 4; ++q) CM[q] = __expf(trans[tg[q] * LL + tg[q - 1]]);

        float A0 = (l == 0) ? __expf(inputs[(size_t)b * LL + tg[0]]) : 0.f;
        float A1 = 0.f, A2 = 0.f, A3 = 0.f;
        float m  = (l == 0) ? 0.f : NEGF;
        float Sin;
        FAC_BOUNDARY_S();
        for (int p = 0; p < nph; p += 2) {
          BARX();
          { const int rem = nsteps - 32 * p;
            if (rem >= 32) { FACF_CON32(0); } else { FACF_TAIL32(0, rem); } }
          BARX();
          if (p + 1 < nph) {
            const int rem = nsteps - 32 * (p + 1);
            if (rem >= 32) { FACF_CON32(1); } else { FACF_TAIL32(1, rem); }
          }
        }
        P[OF_FACF + 4 * l + 0] = A0;
        P[OF_FACF + 4 * l + 1] = A1;
        P[OF_FACF + 4 * l + 2] = A2;
        P[OF_FACF + 4 * l + 3] = A3;
        P[OF_FACF + 256 + l]   = m;
      } else {
        CM[0] = __expf(trans[tg[1] * LL + tg[0]]);
        CM[1] = __expf(trans[tg[2] * LL + tg[1]]);
        CM[2] = __expf(trans[tg[3] * LL + tg[2]]);
        int tgn3 = (l < 63) ? targets[b * SS + 4 * l + 4] : 0;
        CM[3] = (l < 63) ? __expf(trans[tgn3 * LL + tg[3]]) : 0.f;

        const int tl = tlen[b];
        const int fs = tl - 1;
        float A0 = (4 * l + 0 == fs) ? 1.f : 0.f;
        float A1 = (4 * l + 1 == fs) ? 1.f : 0.f;
        float A2 = (4 * l + 2 == fs) ? 1.f : 0.f;
        float A3 = (4 * l + 3 == fs) ? 1.f : 0.f;
        float m  = (l == (fs >> 2)) ? 0.f : NEGF;
        float Sb;
        FACB_BOUNDARY_S();
        for (int p = 0; p < nph; p += 2) {
          BARX();
          FACB_CON32(0);
          BARX();
          if (p + 1 < nph) { FACB_CON32(1); }
        }
        P[OF_FACB + 4 * l + 0] = A0;
        P[OF_FACB + 4 * l + 1] = A1;
        P[OF_FACB + 4 * l + 2] = A2;
        P[OF_FACB + 4 * l + 3] = A3;
        P[OF_FACB + 256 + l]   = m;
      }
    } else {
      // ---- 2 helper waves: 8 pairs (16 rows) each, 3-deep prefetch ----
      const int kh = 8 * (w - 1);          // pair indices kh..kh+7
      int adA[4], adB[4];
      #pragma unroll
      for (int j = 0; j < 4; ++j) {
        int tg = targets[b * SS + 4 * l + j];
        adA[j] = tg * 4; adB[j] = adA[j] + 128;
      }
      float R1[8], R2[8], R3[8];
      #pragma unroll
      for (int k = 0; k < 8; ++k) R1[k] = FHLD32(0, kh + k);
      #pragma unroll
      for (int k = 0; k < 8; ++k) R2[k] = FHLD32(1, kh + k);
      #pragma unroll
      for (int k = 0; k < 8; ++k) R3[k] = FHLD32(2, kh + k);
      #pragma unroll
      for (int k = 0; k < 8; ++k) PRODE(0, kh + k, R1[k]);
      #pragma unroll
      for (int k = 0; k < 8; ++k) { R1[k] = R2[k]; R2[k] = R3[k]; R3[k] = FHLD32(3, kh + k); }

      for (int p = 0; p < nph; p += 2) {
        BARX();
        if (p + 1 < nph) {
          float N[8];
          #pragma unroll
          for (int k = 0; k < 8; ++k) N[k] = FHLD32(p + 4, kh + k);
          #pragma unroll
          for (int k = 0; k < 8; ++k) PRODE(1, kh + k, R1[k]);
          #pragma unroll
          for (int k = 0; k < 8; ++k) { R1[k] = R2[k]; R2[k] = R3[k]; R3[k] = N[k]; }
        }
        BARX();
        if (p + 2 < nph) {
          float N[8];
          #pragma unroll
          for (int k = 0; k < 8; ++k) N[k] = FHLD32(p + 5, kh + k);
          #pragma unroll
          for (int k = 0; k < 8; ++k) PRODE(0, kh + k, R1[k]);
          #pragma unroll
          for (int k = 0; k < 8; ++k) { R1[k] = R2[k]; R2[k] = R3[k]; R3[k] = N[k]; }
        }
      }
    }
    return;
  }

  // ================= FCC chunk scans (3 indep waves / block) ===========
  const int cid = bid - 2 * TB;
  const int sid = 3 * cid + w;     // 0..1919
  const int s = sid >> 6;          // scan id 0..NSCAN-1
  const int b = sid & 63;
  const int len = ilen[b];
  const int lenm1 = len - 1;
  const int Lsteps = lenm1;
  int L = ((Lsteps / NCH) + 4) & ~7;           // balanced chunk length
  if ((NCH - 1) * L > Lsteps) L = (Lsteps / NCH) & ~7;
  const int n0 = Lsteps - (NCH - 1) * L;       // chunk0 length (has tail)

  bool isfwd; int t0 = 1, thi = lenm1, nsteps, outslot;
  if (s == 0)      { isfwd = true;  t0 = 1; nsteps = n0; outslot = 0; }
  else if (s == 1) { isfwd = false; thi = lenm1; nsteps = L; outslot = 1; }
  else {
    const int j = s >> 1;                      // 1..NI
    if ((s & 1) == 0) { isfwd = true;  t0 = n0 + (j - 1) * L + 1; nsteps = L; outslot = 2 * j; }
    else              { isfwd = false; thi = n0 + j * L;          nsteps = L; outslot = 2 * j + 1; }
  }
  const float* gpl = inputs + (size_t)b * LL + lam1;
  float* P = ws + (size_t)b * WSB + OF_FCC + outslot * 33;

  const int adE = lam2 * 4;         // even step gather addr
  const int adO = 128 + lam1 * 4;   // odd step gather addr

  if (isfwd) {
    float Ec1[16], Ec2[16];
    Ec1[0] = __expf(trans[lam2 * LL + lam1]);
    Ec2[0] = __expf(trans[lam1 * LL + lam2]);
    Calib<1>::run(trans, lam1, lam2, Ec1);
    Calib<1>::run(trans, lam2, lam1, Ec2);
    float A = (s == 0) ? __expf(inputs[(size_t)b * LL + lam1]) : 1.f;
    int Kt = 0;
    int t = t0;
    const int tend = t0 + nsteps;
    float R0_[4], R1_[4], R2_[4];
    LDBLK(R0_, t); LDBLK(R1_, t + 8); LDBLK(R2_, t + 16);
    for (;;) {
      if (t + 8 > tend) break;
      FCC_BLOCK8(R0_); LDBLK(R0_, t + 24); t += 8;
      if (t + 8 > tend) break;
      FCC_BLOCK8(R1_); LDBLK(R1_, t + 24); t += 8;
      if (t + 8 > tend) break;
      FCC_BLOCK8(R2_); LDBLK(R2_, t + 24); t += 8;
    }
    if (t < tend) {  // tail (<8 steps)
      float RT[4];
      LDBLK(RT, t);
      float eb[8];
      #pragma unroll
      for (int k = 0; k < 4; ++k) {
        float e_ = __expf(RT[k]);
        eb[2 * k]     = bperm(adE, e_);
        eb[2 * k + 1] = bperm(adO, e_);
      }
      #pragma unroll
      for (int q = 0; q < 8; ++q) {
        if (t + q >= tend) break;
        if ((q & 1) == 0) { float part; STEP16(Ec1); A = eb[q] * xsum16(part); }
        else              { float part; STEP16(Ec2); A = eb[q] * xsum32(part); }
      }
    }
    const int par = nsteps & 1;
    const int idx = par ? lam2 : lam1;
    const bool wr = par ? ((l & 16) == 0) : (l < 32);
    if (wr) P[idx] = A;
    if (l == 0) P[32] = (float)Kt;

  } else {
    float E1T[16], E2T[16];
    E1T[0] = __expf(trans[lam1 * LL + lam2]);
    E2T[0] = __expf(trans[lam2 * LL + lam1]);
    CalibT<1>::run(trans, lam1, lam2, E1T);
    CalibT<1>::run(trans, lam2, lam1, E2T);
    float A = 1.f;
    int Kt = 0;
    int th = thi;
    int rem = nsteps;               // multiple of 8
    float R0_[4], R1_[4], R2_[4];
    LDBLKD(R0_, th - 7); LDBLKD(R1_, th - 15); LDBLKD(R2_, th - 23);
    for (;;) {
      if (rem < 8) break;
      FCC_BWDBLK8(R0_); LDBLKD(R0_, th - 31); th -= 8; rem -= 8;
      if (rem < 8) break;
      FCC_BWDBLK8(R1_); LDBLKD(R1_, th - 31); th -= 8; rem -= 8;
      if (rem < 8) break;
      FCC_BWDBLK8(R2_); LDBLKD(R2_, th - 31); th -= 8; rem -= 8;
    }
    if (l < 32) P[lam1] = A;        // L even -> lam1 layout
    if (l == 0) P[32] = (float)Kt;
  }
}

// ======================= combine ========================================

extern "C" __global__ __launch_bounds__(1024)
void asg_combine(const float* __restrict__ ws, float* __restrict__ out) {
  __shared__ float sd[TB];
  const int tid = (int)threadIdx.x;
  const int w = tid >> 6, l = tid & 63;

  for (int k = 0; k < 4; ++k) {
    const int b = w * 4 + k;
    const float* P = ws + (size_t)b * WSB;

    // ---- FCC: telescoped rank-1 chunk products ----
    float acc = 0.f;
    float Ksum = P[OF_FCC + 0 * 33 + 32];           // Ka
    for (int j = 0; j <= NI; ++j) {
      const int qs = (j == NI) ? 1 : (2 * j + 3);   // q_{j+1}, last = c
      const int ps = (j == 0) ? 0 : (2 * j);        // p_j, first = a
      float qv = (l < 32) ? P[OF_FCC + qs * 33 + l] : 0.f;
      float pv = (l < 32) ? P[OF_FCC + ps * 33 + l] : 0.f;
      float d = qv * pv;
      #pragma unroll
      for (int mm = 1; mm < 64; mm <<= 1) d += __shfl_xor(d, mm);
      acc += __logf(d);
      Ksum += P[OF_FCC + qs * 33 + 32];             // Kq (or Kc)
    }
    for (int j = 1; j <= NI; ++j) {
      float pv = (l < 32) ? P[OF_FCC + 2 * j * 33 + l] : 0.f;
      #pragma unroll
      for (int mm = 1; mm < 64; mm <<= 1) pv += __shfl_xor(pv, mm);
      acc -= __logf(pv);
    }
    float fcc = acc + Ksum * LN2F;

    // ---- FAC: score = sum_s alpha[s] * beta[s] ----
    float pa = P[OF_FACF + 4 * l + 0] * P[OF_FACB + 4 * l + 0]
             + P[OF_FACF + 4 * l + 1] * P[OF_FACB + 4 * l + 1]
             + P[OF_FACF + 4 * l + 2] * P[OF_FACB + 4 * l + 2]
             + P[OF_FACF + 4 * l + 3] * P[OF_FACB + 4 * l + 3];
    float sc = P[OF_FACF + 256 + l] + P[OF_FACB + 256 + l];
    float Ms = sc;
    #pragma unroll
    for (int mm = 1; mm < 64; mm <<= 1) Ms = fmaxf(Ms, __shfl_xor(Ms, mm));
    float pp = pa * exp2f(sc - Ms);
    #pragma unroll
    for (int mm = 1; mm < 64; mm <<= 1) pp += __shfl_xor(pp, mm);
    float fac = __logf(pp) + Ms * LN2F;

    if (l == 0) sd[b] = fcc - fac;
  }
  __syncthreads();
  if (tid < TB) {
    float d = sd[tid];
    #pragma unroll
    for (int mm = 1; mm < 64; mm <<= 1) d += __shfl_xor(d, mm);
    if (tid == 0) out[0] = d * (1.0f / TB);
  }
}

// ======================= launcher =======================================

extern "C" void kernel_launch(void* const* d_in, const int* in_sizes, int n_in,
                              void* d_out, int out_size, void* d_ws, size_t ws_size,
                              hipStream_t stream) {
  const float* trans   = (const float*)d_in[0];
  const float* inputs  = (const float*)d_in[1];
  const int*   targets = (const int*)d_in[2];
  const int*   ilen    = (const int*)d_in[3];
  const int*   tlen    = (const int*)d_in[4];
  float* out = (float*)d_out;
  float* ws  = (float*)d_ws;

  // 128 FAC blocks (chain + 2 helpers) + 640 FCC blocks (3 scans each)
  asg_main<<<dim3(2 * TB + (NSCAN * TB) / 3), dim3(192), 0, stream>>>(
      trans, inputs, targets, ilen, tlen, ws);
  asg_combine<<<dim3(1), dim3(1024), 0, stream>>>(ws, out);
}

// Round 9
// 77.366 us; speedup vs baseline: 2.2021x; 1.4987x over previous
//
#include <hip/hip_runtime.h>
#include <math.h>

static constexpr int TB = 64;   // batch
static constexpr int LL = 32;   // labels
static constexpr int SS = 256;  // max target length
static constexpr int STRIDE_T = TB * LL;  // floats per time step (2048)

// FCC chunking: NCH chunks -> chunk0 (fwd, init), NI interior (fwd+bwd), last (bwd)
static constexpr int NCH = 16;
static constexpr int NI  = NCH - 2;             // 14 interior
static constexpr int NSCAN = 2 + 2 * NI;        // 30 scans per batch

// ---- workspace layout (floats per batch) --------------------------------
// FCC slots (33 floats): 0=a, 1=c, 2j=p_j, 2j+1=q_j (j=1..NI)
static constexpr int OF_FCC  = 0;               // 30*33 = 990
static constexpr int OF_FACF = 992;             // 256 vals + 64 scales
static constexpr int OF_FACB = 1312;            // 256 vals + 64 scales
static constexpr int WSB     = 1632;            // per-batch stride
static constexpr int OF_DIFF = TB * WSB;        // per-batch diff (64 floats)

#define LN2F 0.69314718055994530942f
#define NEGF (-1e30f)
#define SBAR() __builtin_amdgcn_sched_barrier(0)

// raw barrier: waits LDS only (keeps global-load prefetch in flight)
#define BARX() { asm volatile("s_waitcnt lgkmcnt(0)" ::: "memory"); \
                 __builtin_amdgcn_s_barrier(); \
                 asm volatile("" ::: "memory"); }

// ---- DPP / cross-lane helpers ------------------------------------------
template<int CTL>
__device__ __forceinline__ float dpp_f(float x, float oldv) {
  return __int_as_float(__builtin_amdgcn_update_dpp(
      __float_as_int(oldv), __float_as_int(x), CTL, 0xF, 0xF, false));
}
template<int M>
__device__ __forceinline__ int rot_i(int x) {
  return __builtin_amdgcn_update_dpp(0, x, 0x120 + M, 0xF, 0xF, false); // row_ror:M
}

typedef unsigned uint2v __attribute__((ext_vector_type(2)));
__device__ __forceinline__ float xsum16(float x) {  // x[l] + x[l^16]
  uint2v r = __builtin_amdgcn_permlane16_swap(__float_as_uint(x), __float_as_uint(x), false, false);
  return __uint_as_float(r.x) + __uint_as_float(r.y);
}
__device__ __forceinline__ float xsum32(float x) {  // x[l] + x[l^32]
  uint2v r = __builtin_amdgcn_permlane32_swap(__float_as_uint(x), __float_as_uint(x), false, false);
  return __uint_as_float(r.x) + __uint_as_float(r.y);
}
__device__ __forceinline__ float bperm(int addr, float src) {  // pull lane addr>>2
  return __int_as_float(__builtin_amdgcn_ds_bpermute(addr, __float_as_int(src)));
}

// Self-calibrating coefficient load (rot_i matches row_ror:M exactly)
template<int M>
struct Calib {
  __device__ static __forceinline__ void run(const float* trans, int lam, int i, float* Ec) {
    Ec[M] = __expf(trans[i * LL + rot_i<M>(lam)]);
    Calib<M + 1>::run(trans, lam, i, Ec);
  }
};
template<> struct Calib<16> {
  __device__ static __forceinline__ void run(const float*, int, int, float*) {}
};
// Transposed variant: coefficient trans[rot(lam)][i]  (M^T matvec)
template<int M>
struct CalibT {
  __device__ static __forceinline__ void run(const float* trans, int lam, int i, float* Ec) {
    Ec[M] = __expf(trans[rot_i<M>(lam) * LL + i]);
    CalibT<M + 1>::run(trans, lam, i, Ec);
  }
};
template<> struct CalibT<16> {
  __device__ static __forceinline__ void run(const float*, int, int, float*) {}
};

// ---- fused rotate-multiply asm (1 instr per term) -----------------------
#define ROT_MUL(DST, SRC, COEF, ROT) \
  asm("v_mul_f32_dpp %0, %1, %2 row_ror:" #ROT " row_mask:0xf bank_mask:0xf" \
      : "=v"(DST) : "v"(SRC), "v"(COEF))
#define ROT_FMAC(ACC, SRC, COEF, ROT) \
  asm("v_fmac_f32_dpp %0, %1, %2 row_ror:" #ROT " row_mask:0xf bank_mask:0xf" \
      : "+v"(ACC) : "v"(SRC), "v"(COEF))

// matvec over 16-lane rows: 8 indep chains of depth 2, then 3-level tree
#define STEP16(EC) { \
  float a0 = EC[0] * A, a1, a2, a3, a4, a5, a6, a7; \
  ROT_MUL(a1, A, EC[1], 1); ROT_MUL(a2, A, EC[2], 2); ROT_MUL(a3, A, EC[3], 3); \
  ROT_MUL(a4, A, EC[4], 4); ROT_MUL(a5, A, EC[5], 5); ROT_MUL(a6, A, EC[6], 6); \
  ROT_MUL(a7, A, EC[7], 7); \
  ROT_FMAC(a0, A, EC[8], 8);   ROT_FMAC(a1, A, EC[9], 9); \
  ROT_FMAC(a2, A, EC[10], 10); ROT_FMAC(a3, A, EC[11], 11); \
  ROT_FMAC(a4, A, EC[12], 12); ROT_FMAC(a5, A, EC[13], 13); \
  ROT_FMAC(a6, A, EC[14], 14); ROT_FMAC(a7, A, EC[15], 15); \
  part = ((a0 + a1) + (a2 + a3)) + ((a4 + a5) + (a6 + a7)); }

// ======================= FCC (self-feeding, register staging) ============

#define FCC_RENORM() { \
  unsigned uu = (unsigned)__builtin_amdgcn_readfirstlane((int)__float_as_uint(A)); \
  int ex = (int)((uu >> 23) & 255) - 127; \
  A = ldexpf(A, -ex); Kt += ex; }

// coalesced loads of rows t..t+7 (2 rows/instr via rowoff); clamp high
#define LDBLK(R, TBASE) { \
  _Pragma("unroll") for (int k = 0; k < 4; ++k) { \
    int tt = (TBASE) + 2 * k + rowoff; tt = tt > lenm1 ? lenm1 : tt; \
    R[k] = gpl[(size_t)tt * STRIDE_T]; } \
  SBAR(); }
// descending variant: clamp both ends
#define LDBLKD(R, TBASE) { \
  _Pragma("unroll") for (int k = 0; k < 4; ++k) { \
    int tt = (TBASE) + 2 * k + rowoff; \
    tt = tt < 0 ? 0 : (tt > lenm1 ? lenm1 : tt); \
    R[k] = gpl[(size_t)tt * STRIDE_T]; } \
  SBAR(); }

#define FCC_BLOCK8(R) { \
  float eb[8]; \
  _Pragma("unroll") for (int k = 0; k < 4; ++k) { \
    float e_ = __expf(R[k]); \
    eb[2 * k]     = bperm(adE, e_); \
    eb[2 * k + 1] = bperm(adO, e_); } \
  { float part; STEP16(Ec1); A = eb[0] * xsum16(part); } \
  { float part; STEP16(Ec2); A = eb[1] * xsum32(part); } \
  { float part; STEP16(Ec1); A = eb[2] * xsum16(part); } \
  { float part; STEP16(Ec2); A = eb[3] * xsum32(part); } \
  { float part; STEP16(Ec1); A = eb[4] * xsum16(part); } \
  { float part; STEP16(Ec2); A = eb[5] * xsum32(part); } \
  { float part; STEP16(Ec1); A = eb[6] * xsum16(part); } \
  { float part; STEP16(Ec2); A = eb[7] * xsum32(part); } \
  FCC_RENORM(); }

// backward (transpose): consumes rows 7..0; emission multiplies BEFORE matvec
#define FCC_BWDBLK8(R) { \
  float eb[8]; \
  _Pragma("unroll") for (int k = 0; k < 4; ++k) { \
    float e_ = __expf(R[k]); \
    eb[2 * k]     = bperm(adE, e_); \
    eb[2 * k + 1] = bperm(adO, e_); } \
  { A *= eb[7]; float part; STEP16(E1T); A = xsum16(part); } \
  { A *= eb[6]; float part; STEP16(E2T); A = xsum32(part); } \
  { A *= eb[5]; float part; STEP16(E1T); A = xsum16(part); } \
  { A *= eb[4]; float part; STEP16(E2T); A = xsum32(part); } \
  { A *= eb[3]; float part; STEP16(E1T); A = xsum16(part); } \
  { A *= eb[2]; float part; STEP16(E2T); A = xsum32(part); } \
  { A *= eb[1]; float part; STEP16(E1T); A = xsum16(part); } \
  { A *= eb[0]; float part; STEP16(E2T); A = xsum32(part); } \
  FCC_RENORM(); }

// ======================= FAC (E-only LDS staging, 32-step phases) =======
// sFE[.][r][l] = {E[tg0],E[tg1],E[tg2],E[tg3]} gathered for lane l at row r.

#define FAC_BOUNDARY_S() { \
  float maxA = fmaxf(fmaxf(A0, A1), fmaxf(A2, A3)); \
  if (maxA > 0.f) { \
    int ex = (int)((__float_as_uint(maxA) >> 23) & 255) - 127; \
    A0 = ldexpf(A0, -ex); A1 = ldexpf(A1, -ex); \
    A2 = ldexpf(A2, -ex); A3 = ldexpf(A3, -ex); \
    m += (float)ex; \
  } \
  float mp = dpp_f<0x138>(m, NEGF); m = (m == NEGF) ? mp : m; \
  mp = dpp_f<0x138>(m, NEGF);       m = (m == NEGF) ? mp : m; \
  mp = dpp_f<0x138>(m, NEGF); \
  float dlt = fminf(mp - m, 50.0f); \
  Sin = exp2f(dlt); }

#define FSTEPE(R) { \
  float c0 = Er[R].x * ST[0], c1 = Er[R].y * ST[1]; \
  float c2 = Er[R].z * ST[2], c3 = Er[R].w * ST[3]; \
  float v0 = Er[R].x * CM[0], v1 = Er[R].y * CM[1]; \
  float v2 = Er[R].z * CM[2], v3 = Er[R].w * CM[3]; \
  float ap = dpp_f<0x138>(A3, 0.f); /* wave_shr:1 */ \
  float n0 = fmaf(v0 * Sin, ap, c0 * A0); \
  float n1 = fmaf(v1, A0, c1 * A1); \
  float n2 = fmaf(v2, A1, c2 * A2); \
  float n3 = fmaf(v3, A2, c3 * A3); \
  A0 = n0; A1 = n1; A2 = n2; A3 = n3; }

#define FRD16(PB, BASE) { \
  _Pragma("unroll") for (int r = 0; r < 16; ++r) Er[r] = sFE[PB][(BASE) + r][l]; }

#define FSTE8A() { FSTEPE(0); FSTEPE(1); FSTEPE(2); FSTEPE(3); \
                   FSTEPE(4); FSTEPE(5); FSTEPE(6); FSTEPE(7); }
#define FSTE8B() { FSTEPE(8); FSTEPE(9); FSTEPE(10); FSTEPE(11); \
                   FSTEPE(12); FSTEPE(13); FSTEPE(14); FSTEPE(15); }

#define FACF_CON32(PB) { \
  float4 Er[16]; \
  FRD16(PB, 0); \
  FSTE8A(); FAC_BOUNDARY_S(); \
  FSTE8B(); FAC_BOUNDARY_S(); \
  FRD16(PB, 16); \
  FSTE8A(); FAC_BOUNDARY_S(); \
  FSTE8B(); FAC_BOUNDARY_S(); }

#define FACF_TAIL32(PB, CNT) { \
  float4 Er[16]; \
  FRD16(PB, 0); \
  _Pragma("unroll") for (int r = 0; r < 16; ++r) { \
    if (r >= (CNT)) break; \
    FSTEPE(r); \
    if (r == 7) { FAC_BOUNDARY_S(); } } \
  if ((CNT) > 16) { \
    FAC_BOUNDARY_S(); \
    FRD16(PB, 16); \
    _Pragma("unroll") for (int r = 0; r < 16; ++r) { \
      if (r + 16 >= (CNT)) break; \
      FSTEPE(r); \
      if (r == 7) { FAC_BOUNDARY_S(); } } } }

#define FACB_BOUNDARY_S() { \
  float maxA = fmaxf(fmaxf(A0, A1), fmaxf(A2, A3)); \
  if (maxA > 0.f) { \
    int ex = (int)((__float_as_uint(maxA) >> 23) & 255) - 127; \
    A0 = ldexpf(A0, -ex); A1 = ldexpf(A1, -ex); \
    A2 = ldexpf(A2, -ex); A3 = ldexpf(A3, -ex); \
    m += (float)ex; \
  } \
  float mp = dpp_f<0x130>(m, NEGF); m = (m == NEGF) ? mp : m; \
  mp = dpp_f<0x130>(m, NEGF);       m = (m == NEGF) ? mp : m; \
  mp = dpp_f<0x130>(m, NEGF); \
  float dlt = fminf(mp - m, 50.0f); \
  Sb = exp2f(dlt); }

#define FBSTEPE(R) { \
  float c0 = Er[R].x * ST[0], c1 = Er[R].y * ST[1]; \
  float c2 = Er[R].z * ST[2], c3 = Er[R].w * ST[3]; \
  float w0 = Er[R].y * CM[0], w1 = Er[R].z * CM[1], w2 = Er[R].w * CM[2]; \
  float en3 = dpp_f<0x130>(Er[R].x, 0.f); /* wave_shl:1 */ \
  float w3 = en3 * CM[3]; \
  float an = dpp_f<0x130>(A0, 0.f); \
  float n0 = fmaf(w0, A1, c0 * A0); \
  float n1 = fmaf(w1, A2, c1 * A1); \
  float n2 = fmaf(w2, A3, c2 * A2); \
  float n3 = fmaf(w3 * Sb, an, c3 * A3); \
  A0 = n0; A1 = n1; A2 = n2; A3 = n3; }

#define FBST8D() { FBSTEPE(15); FBSTEPE(14); FBSTEPE(13); FBSTEPE(12); \
                   FBSTEPE(11); FBSTEPE(10); FBSTEPE(9);  FBSTEPE(8); }
#define FBST8L() { FBSTEPE(7);  FBSTEPE(6);  FBSTEPE(5);  FBSTEPE(4); \
                   FBSTEPE(3);  FBSTEPE(2);  FBSTEPE(1);  FBSTEPE(0); }

#define FACB_CON32(PB) { \
  float4 Er[16]; \
  FRD16(PB, 16); \
  FBST8D(); FACB_BOUNDARY_S(); \
  FBST8L(); FACB_BOUNDARY_S(); \
  FRD16(PB, 0); \
  FBST8D(); FACB_BOUNDARY_S(); \
  FBST8L(); FACB_BOUNDARY_S(); }

// ======================= FAC staging loads ==============================

// 32-row phases: pair K = 0..15
#define FHLD32(Q, K) ({ \
  int tt_ = (isfwd ? (1 + 32 * (Q)) : (lenm1 - 32 * (Q) - 31)) + 2 * (K) + rowoff; \
  tt_ = tt_ < 0 ? 0 : (tt_ > lenm1 ? lenm1 : tt_); \
  gpl[(size_t)tt_ * STRIDE_T]; })

// gather-only produce: one loaded value covers 2 rows (lane halves)
#define PRODE(PB, KK, RV) { \
  float e_ = __expf(RV); \
  float4 E0_, E1_; \
  E0_.x = bperm(adA[0], e_); E0_.y = bperm(adA[1], e_); \
  E0_.z = bperm(adA[2], e_); E0_.w = bperm(adA[3], e_); \
  E1_.x = bperm(adB[0], e_); E1_.y = bperm(adB[1], e_); \
  E1_.z = bperm(adB[2], e_); E1_.w = bperm(adB[3], e_); \
  sFE[PB][2 * (KK)][l]     = E0_; \
  sFE[PB][2 * (KK) + 1][l] = E1_; }

// ======================= main kernel ====================================
// grid: [0,128)     = FAC halves (chain + 2 helpers, 32-step phases)
//       [128,768)   = FCC chunk scans (3 independent self-feeding waves/block)

extern "C" __global__ __launch_bounds__(192, 1)
void asg_main(const float* __restrict__ trans, const float* __restrict__ inputs,
              const int* __restrict__ targets, const int* __restrict__ ilen,
              const int* __restrict__ tlen, float* __restrict__ ws) {
  const int tid = (int)threadIdx.x;
  const int w = tid >> 6;
  const int l = tid & 63;
  const int lam1 = l & 31;
  const int lam2 = (l & 15) | ((l >> 5) << 4);
  const int rowoff = l >> 5;
  const int bid = (int)blockIdx.x;

  __shared__ float4 sFE[2][32][64];  // FAC gathered-E staging (64 KB)

  if (bid < 2 * TB) {
    // ================= FAC halves ====================================
    const int role = bid >> 6;   // 0 fwd, 1 bwd
    const int b    = bid & 63;
    const int len = ilen[b];
    const int lenm1 = len - 1;
    const int Lsteps = lenm1;
    const int nbf = (Lsteps / 2) & ~31;    // bwd steps (mult of 32, no tail)
    const int nff = Lsteps - nbf;          // fwd steps (tail ok)
    const bool isfwd = (role == 0);
    const int nsteps = isfwd ? nff : nbf;
    const int nph = (nsteps + 31) >> 5;
    const float* gpl = inputs + (size_t)b * LL + lam1;
    float* P = ws + (size_t)b * WSB;

    if (w == 0) {
      // ---- chain wave ----
      __builtin_amdgcn_s_setprio(1);
      int tg[4];
      #pragma unroll
      for (int q = 0; q < 4; ++q) tg[q] = targets[b * SS + 4 * l + q];
      float ST[4], CM[4];
      #pragma unroll
      for (int q = 0; q < 4; ++q) ST[q] = __expf(trans[tg[q] * LL + tg[q]]);

      if (isfwd) {
        CM[0] = (l == 0) ? 0.f : __expf(trans[tg[0] * LL + targets[b * SS + 4 * l - 1]]);
        #pragma unroll
        for (int q = 1; q < 4; ++q) CM[q] = __expf(trans[tg[q] * LL + tg[q - 1]]);

        float A0 = (l == 0) ? __expf(inputs[(size_t)b * LL + tg[0]]) : 0.f;
        float A1 = 0.f, A2 = 0.f, A3 = 0.f;
        float m  = (l == 0) ? 0.f : NEGF;
        float Sin;
        FAC_BOUNDARY_S();
        for (int p = 0; p < nph; p += 2) {
          BARX();
          { const int rem = nsteps - 32 * p;
            if (rem >= 32) { FACF_CON32(0); } else { FACF_TAIL32(0, rem); } }
          BARX();
          if (p + 1 < nph) {
            const int rem = nsteps - 32 * (p + 1);
            if (rem >= 32) { FACF_CON32(1); } else { FACF_TAIL32(1, rem); }
          }
        }
        P[OF_FACF + 4 * l + 0] = A0;
        P[OF_FACF + 4 * l + 1] = A1;
        P[OF_FACF + 4 * l + 2] = A2;
        P[OF_FACF + 4 * l + 3] = A3;
        P[OF_FACF + 256 + l]   = m;
      } else {
        CM[0] = __expf(trans[tg[1] * LL + tg[0]]);
        CM[1] = __expf(trans[tg[2] * LL + tg[1]]);
        CM[2] = __expf(trans[tg[3] * LL + tg[2]]);
        int tgn3 = (l < 63) ? targets[b * SS + 4 * l + 4] : 0;
        CM[3] = (l < 63) ? __expf(trans[tgn3 * LL + tg[3]]) : 0.f;

        const int tl = tlen[b];
        const int fs = tl - 1;
        float A0 = (4 * l + 0 == fs) ? 1.f : 0.f;
        float A1 = (4 * l + 1 == fs) ? 1.f : 0.f;
        float A2 = (4 * l + 2 == fs) ? 1.f : 0.f;
        float A3 = (4 * l + 3 == fs) ? 1.f : 0.f;
        float m  = (l == (fs >> 2)) ? 0.f : NEGF;
        float Sb;
        FACB_BOUNDARY_S();
        for (int p = 0; p < nph; p += 2) {
          BARX();
          FACB_CON32(0);
          BARX();
          if (p + 1 < nph) { FACB_CON32(1); }
        }
        P[OF_FACB + 4 * l + 0] = A0;
        P[OF_FACB + 4 * l + 1] = A1;
        P[OF_FACB + 4 * l + 2] = A2;
        P[OF_FACB + 4 * l + 3] = A3;
        P[OF_FACB + 256 + l]   = m;
      }
    } else {
      // ---- 2 helper waves: 8 pairs (16 rows) each, 3-deep prefetch ----
      const int kh = 8 * (w - 1);          // pair indices kh..kh+7
      int adA[4], adB[4];
      #pragma unroll
      for (int j = 0; j < 4; ++j) {
        int tg = targets[b * SS + 4 * l + j];
        adA[j] = tg * 4; adB[j] = adA[j] + 128;
      }
      float R1[8], R2[8], R3[8];
      #pragma unroll
      for (int k = 0; k < 8; ++k) R1[k] = FHLD32(0, kh + k);
      #pragma unroll
      for (int k = 0; k < 8; ++k) R2[k] = FHLD32(1, kh + k);
      #pragma unroll
      for (int k = 0; k < 8; ++k) R3[k] = FHLD32(2, kh + k);
      #pragma unroll
      for (int k = 0; k < 8; ++k) PRODE(0, kh + k, R1[k]);
      #pragma unroll
      for (int k = 0; k < 8; ++k) { R1[k] = R2[k]; R2[k] = R3[k]; R3[k] = FHLD32(3, kh + k); }

      for (int p = 0; p < nph; p += 2) {
        BARX();
        if (p + 1 < nph) {
          float N[8];
          #pragma unroll
          for (int k = 0; k < 8; ++k) N[k] = FHLD32(p + 4, kh + k);
          #pragma unroll
          for (int k = 0; k < 8; ++k) PRODE(1, kh + k, R1[k]);
          #pragma unroll
          for (int k = 0; k < 8; ++k) { R1[k] = R2[k]; R2[k] = R3[k]; R3[k] = N[k]; }
        }
        BARX();
        if (p + 2 < nph) {
          float N[8];
          #pragma unroll
          for (int k = 0; k < 8; ++k) N[k] = FHLD32(p + 5, kh + k);
          #pragma unroll
          for (int k = 0; k < 8; ++k) PRODE(0, kh + k, R1[k]);
          #pragma unroll
          for (int k = 0; k < 8; ++k) { R1[k] = R2[k]; R2[k] = R3[k]; R3[k] = N[k]; }
        }
      }
    }
    return;
  }

  // ================= FCC chunk scans (3 indep waves / block) ===========
  const int cid = bid - 2 * TB;
  const int sid = 3 * cid + w;     // 0..1919
  const int s = sid >> 6;          // scan id 0..NSCAN-1
  const int b = sid & 63;
  const int len = ilen[b];
  const int lenm1 = len - 1;
  const int Lsteps = lenm1;
  int L = ((Lsteps / NCH) + 4) & ~7;           // balanced chunk length
  if ((NCH - 1) * L > Lsteps) L = (Lsteps / NCH) & ~7;
  const int n0 = Lsteps - (NCH - 1) * L;       // chunk0 length (has tail)

  bool isfwd; int t0 = 1, thi = lenm1, nsteps, outslot;
  if (s == 0)      { isfwd = true;  t0 = 1; nsteps = n0; outslot = 0; }
  else if (s == 1) { isfwd = false; thi = lenm1; nsteps = L; outslot = 1; }
  else {
    const int j = s >> 1;                      // 1..NI
    if ((s & 1) == 0) { isfwd = true;  t0 = n0 + (j - 1) * L + 1; nsteps = L; outslot = 2 * j; }
    else              { isfwd = false; thi = n0 + j * L;          nsteps = L; outslot = 2 * j + 1; }
  }
  const float* gpl = inputs + (size_t)b * LL + lam1;
  float* P = ws + (size_t)b * WSB + OF_FCC + outslot * 33;

  const int adE = lam2 * 4;         // even step gather addr
  const int adO = 128 + lam1 * 4;   // odd step gather addr

  if (isfwd) {
    float Ec1[16], Ec2[16];
    Ec1[0] = __expf(trans[lam2 * LL + lam1]);
    Ec2[0] = __expf(trans[lam1 * LL + lam2]);
    Calib<1>::run(trans, lam1, lam2, Ec1);
    Calib<1>::run(trans, lam2, lam1, Ec2);
    float A = (s == 0) ? __expf(inputs[(size_t)b * LL + lam1]) : 1.f;
    int Kt = 0;
    int t = t0;
    const int tend = t0 + nsteps;
    float R0_[4], R1_[4], R2_[4];
    LDBLK(R0_, t); LDBLK(R1_, t + 8); LDBLK(R2_, t + 16);
    for (;;) {
      if (t + 8 > tend) break;
      FCC_BLOCK8(R0_); LDBLK(R0_, t + 24); t += 8;
      if (t + 8 > tend) break;
      FCC_BLOCK8(R1_); LDBLK(R1_, t + 24); t += 8;
      if (t + 8 > tend) break;
      FCC_BLOCK8(R2_); LDBLK(R2_, t + 24); t += 8;
    }
    if (t < tend) {  // tail (<8 steps)
      float RT[4];
      LDBLK(RT, t);
      float eb[8];
      #pragma unroll
      for (int k = 0; k < 4; ++k) {
        float e_ = __expf(RT[k]);
        eb[2 * k]     = bperm(adE, e_);
        eb[2 * k + 1] = bperm(adO, e_);
      }
      #pragma unroll
      for (int q = 0; q < 8; ++q) {
        if (t + q >= tend) break;
        if ((q & 1) == 0) { float part; STEP16(Ec1); A = eb[q] * xsum16(part); }
        else              { float part; STEP16(Ec2); A = eb[q] * xsum32(part); }
      }
    }
    const int par = nsteps & 1;
    const int idx = par ? lam2 : lam1;
    const bool wr = par ? ((l & 16) == 0) : (l < 32);
    if (wr) P[idx] = A;
    if (l == 0) P[32] = (float)Kt;

  } else {
    float E1T[16], E2T[16];
    E1T[0] = __expf(trans[lam1 * LL + lam2]);
    E2T[0] = __expf(trans[lam2 * LL + lam1]);
    CalibT<1>::run(trans, lam1, lam2, E1T);
    CalibT<1>::run(trans, lam2, lam1, E2T);
    float A = 1.f;
    int Kt = 0;
    int th = thi;
    int rem = nsteps;               // multiple of 8
    float R0_[4], R1_[4], R2_[4];
    LDBLKD(R0_, th - 7); LDBLKD(R1_, th - 15); LDBLKD(R2_, th - 23);
    for (;;) {
      if (rem < 8) break;
      FCC_BWDBLK8(R0_); LDBLKD(R0_, th - 31); th -= 8; rem -= 8;
      if (rem < 8) break;
      FCC_BWDBLK8(R1_); LDBLKD(R1_, th - 31); th -= 8; rem -= 8;
      if (rem < 8) break;
      FCC_BWDBLK8(R2_); LDBLKD(R2_, th - 31); th -= 8; rem -= 8;
    }
    if (l < 32) P[lam1] = A;        // L even -> lam1 layout
    if (l == 0) P[32] = (float)Kt;
  }
}

// ======================= combine (parallel, 1 block per batch) ==========

extern "C" __global__ __launch_bounds__(64)
void asg_combineA(const float* __restrict__ ws, float* __restrict__ wdiff) {
  const int b = (int)blockIdx.x;
  const int l = (int)threadIdx.x;
  const float* P = ws + (size_t)b * WSB;

  // ---- FCC: telescoped rank-1 chunk products ----
  float acc = 0.f;
  float Ksum = P[OF_FCC + 0 * 33 + 32];           // Ka
  #pragma unroll
  for (int j = 0; j <= NI; ++j) {
    const int qs = (j == NI) ? 1 : (2 * j + 3);   // q_{j+1}, last = c
    const int ps = (j == 0) ? 0 : (2 * j);        // p_j, first = a
    float qv = (l < 32) ? P[OF_FCC + qs * 33 + l] : 0.f;
    float pv = (l < 32) ? P[OF_FCC + ps * 33 + l] : 0.f;
    float d = qv * pv;
    #pragma unroll
    for (int mm = 1; mm < 64; mm <<= 1) d += __shfl_xor(d, mm);
    acc += __logf(d);
    Ksum += P[OF_FCC + qs * 33 + 32];             // Kq (or Kc)
  }
  #pragma unroll
  for (int j = 1; j <= NI; ++j) {
    float pv = (l < 32) ? P[OF_FCC + 2 * j * 33 + l] : 0.f;
    #pragma unroll
    for (int mm = 1; mm < 64; mm <<= 1) pv += __shfl_xor(pv, mm);
    acc -= __logf(pv);
  }
  float fcc = acc + Ksum * LN2F;

  // ---- FAC: score = sum_s alpha[s] * beta[s] ----
  float pa = P[OF_FACF + 4 * l + 0] * P[OF_FACB + 4 * l + 0]
           + P[OF_FACF + 4 * l + 1] * P[OF_FACB + 4 * l + 1]
           + P[OF_FACF + 4 * l + 2] * P[OF_FACB + 4 * l + 2]
           + P[OF_FACF + 4 * l + 3] * P[OF_FACB + 4 * l + 3];
  float sc = P[OF_FACF + 256 + l] + P[OF_FACB + 256 + l];
  float Ms = sc;
  #pragma unroll
  for (int mm = 1; mm < 64; mm <<= 1) Ms = fmaxf(Ms, __shfl_xor(Ms, mm));
  float pp = pa * exp2f(sc - Ms);
  #pragma unroll
  for (int mm = 1; mm < 64; mm <<= 1) pp += __shfl_xor(pp, mm);
  float fac = __logf(pp) + Ms * LN2F;

  if (l == 0) wdiff[b] = fcc - fac;
}

extern "C" __global__ __launch_bounds__(64)
void asg_combineB(const float* __restrict__ wdiff, float* __restrict__ out) {
  const int l = (int)threadIdx.x;
  float d = wdiff[l];
  #pragma unroll
  for (int mm = 1; mm < 64; mm <<= 1) d += __shfl_xor(d, mm);
  if (l == 0) out[0] = d * (1.0f / TB);
}

// ======================= launcher =======================================

extern "C" void kernel_launch(void* const* d_in, const int* in_sizes, int n_in,
                              void* d_out, int out_size, void* d_ws, size_t ws_size,
                              hipStream_t stream) {
  const float* trans   = (const float*)d_in[0];
  const float* inputs  = (const float*)d_in[1];
  const int*   targets = (const int*)d_in[2];
  const int*   ilen    = (const int*)d_in[3];
  const int*   tlen    = (const int*)d_in[4];
  float* out = (float*)d_out;
  float* ws  = (float*)d_ws;

  // 128 FAC blocks (chain + 2 helpers) + 640 FCC blocks (3 scans each)
  asg_main<<<dim3(2 * TB + (NSCAN * TB) / 3), dim3(192), 0, stream>>>(
      trans, inputs, targets, ilen, tlen, ws);
  asg_combineA<<<dim3(TB), dim3(64), 0, stream>>>(ws, ws + OF_DIFF);
  asg_combineB<<<dim3(1), dim3(64), 0, stream>>>(ws + OF_DIFF, out);
}